// Round 1
// baseline (7972.014 us; speedup 1.0000x reference)
//
#include <hip/hip_runtime.h>
#include <hip/hip_bf16.h>

#define S3 32768          // 32^3
#define PADD 34
#define PADS (34*34*34)   // 39304
#define CC 219
#define CF 64
#define CIN_UP 411
#define ALPHA 0.1f
#define EPS_IN 1e-5f

__device__ __forceinline__ float lrelu(float v){ return v >= 0.f ? v : ALPHA * v; }

// ---------------- plain float4 copy ----------------
__global__ __launch_bounds__(256) void copy4_kernel(const float4* __restrict__ s,
                                                    float4* __restrict__ d, int n4){
    int i = blockIdx.x * 256 + threadIdx.x;
    if (i < n4) d[i] = s[i];
}

// ---------------- zero-pad src to [64][34][34][34] ----------------
__global__ __launch_bounds__(256) void pad_kernel(const float* __restrict__ src,
                                                  float* __restrict__ dst){
    int idx = blockIdx.x * 256 + threadIdx.x;
    if (idx >= CF * PADS) return;
    int c = idx / PADS, r = idx % PADS;
    int z = r / (PADD*PADD); int r2 = r % (PADD*PADD);
    int y = r2 / PADD, x = r2 % PADD;
    float v = 0.f;
    if (z >= 1 && z <= 32 && y >= 1 && y <= 32 && x >= 1 && x <= 32)
        v = src[((c*32 + (z-1))*32 + (y-1))*32 + (x-1)];
    dst[idx] = v;
}

// ---------------- correlation volume: 27 channels into outx[128..154] ----------------
__global__ __launch_bounds__(256) void corr_kernel(const float* __restrict__ tgt,
                                                   const float* __restrict__ srcp,
                                                   float* __restrict__ outx){
    int p = blockIdx.x * 256 + threadIdx.x;   // 0..32767
    int z = p >> 10, y = (p >> 5) & 31, x = p & 31;
    float acc[27];
    #pragma unroll
    for (int k = 0; k < 27; k++) acc[k] = 0.f;
    int pbase = ((z+1)*PADD + (y+1))*PADD + (x+1);
    for (int c = 0; c < CF; c++){
        float t = tgt[c*S3 + p];
        const float* sp = srcp + c*PADS + pbase;
        #pragma unroll
        for (int dz = 0; dz < 3; dz++)
            #pragma unroll
            for (int dy = 0; dy < 3; dy++)
                #pragma unroll
                for (int dx = 0; dx < 3; dx++){
                    int k = (dz*3 + dy)*3 + dx;
                    acc[k] += t * sp[(dz-1)*(PADD*PADD) + (dy-1)*PADD + (dx-1)];
                }
    }
    #pragma unroll
    for (int k = 0; k < 27; k++)
        outx[(size_t)(128 + k)*S3 + p] = acc[k] * (1.f/64.f);
}

// ---------------- transposed conv (411 -> 64, k=4, stride 2, pad "SAME-ish") ----------------
// out[co,z,y,x] = b[co] + sum_ci sum_{jz,jy,jx in {0,1}} C[ci,iz,iy,ix] * up_w[ci,co,3-kz,3-ky,3-kx]
// where k(o,j) = (o&1) + 2*j, i(o,j) = ((o+1)>>1) - 1 + j
__global__ __launch_bounds__(256) void upsample_kernel(const float* __restrict__ Cin,
                                                       const float* __restrict__ up_w,
                                                       const float* __restrict__ up_b,
                                                       float* __restrict__ outp){
    __shared__ float sIn[2*18*18];   // two iz planes, padded 18x18 (zero halo)
    __shared__ float sW[64];
    int co = blockIdx.x >> 5;
    int z  = blockIdx.x & 31;
    int t  = threadIdx.x;
    int y  = t >> 3, x0 = (t & 7) * 4;
    float acc[4] = {0.f, 0.f, 0.f, 0.f};
    int izlo   = ((z + 1) >> 1) - 1;
    int kz_par = z & 1;
    int iylo   = ((y + 1) >> 1) - 1;
    int ky_par = y & 1;
    int ixb    = (x0 >> 1) - 1;

    for (int ci = 0; ci < CIN_UP; ci++){
        if (t < 64) sW[t] = up_w[(ci*64 + co)*64 + t];
        for (int s = t; s < 2*18*18; s += 256){
            int jz = s / 324; int r = s % 324;
            int py = r / 18, px = r % 18;
            int iz = izlo + jz, iy = py - 1, ix = px - 1;
            float v = 0.f;
            if (iz >= 0 && iz < 16 && iy >= 0 && iy < 16 && ix >= 0 && ix < 16)
                v = Cin[((ci*16 + iz)*16 + iy)*16 + ix];
            sIn[s] = v;
        }
        __syncthreads();
        #pragma unroll
        for (int jz = 0; jz < 2; jz++){
            int wzo = (3 - kz_par - 2*jz) * 16;
            #pragma unroll
            for (int jy = 0; jy < 2; jy++){
                int wyo  = (3 - ky_par - 2*jy) * 4;
                int rowb = jz*324 + (iylo + jy + 1)*18;
                float r0 = sIn[rowb + ixb + 1];
                float r1 = sIn[rowb + ixb + 2];
                float r2 = sIn[rowb + ixb + 3];
                float r3 = sIn[rowb + ixb + 4];
                float w3 = sW[wzo + wyo + 3];   // x even, jx=0 (kx=0 -> flipped 3)
                float w1 = sW[wzo + wyo + 1];   // x even, jx=1 (kx=2 -> flipped 1)
                float w2 = sW[wzo + wyo + 2];   // x odd,  jx=0 (kx=1 -> flipped 2)
                float w0 = sW[wzo + wyo + 0];   // x odd,  jx=1 (kx=3 -> flipped 0)
                acc[0] += r0*w3 + r1*w1;
                acc[1] += r1*w2 + r2*w0;
                acc[2] += r1*w3 + r2*w1;
                acc[3] += r2*w2 + r3*w0;
            }
        }
        __syncthreads();
    }
    float b = up_b[co];
    float4 v = make_float4(acc[0]+b, acc[1]+b, acc[2]+b, acc[3]+b);
    *(float4*)(&outp[(size_t)co*S3 + (z<<10) + (y<<5) + x0]) = v;
}

// ---------------- instance-norm stats: one block per channel ----------------
__global__ __launch_bounds__(256) void stats_kernel(const float* __restrict__ xin,
                                                    float* __restrict__ stats, int nch){
    int c = blockIdx.x;
    const float* p = xin + (size_t)c * S3;
    float s = 0.f, s2 = 0.f;
    for (int i = threadIdx.x; i < S3; i += 256){
        float v = p[i];
        s += v; s2 += v*v;
    }
    #pragma unroll
    for (int off = 32; off > 0; off >>= 1){
        s  += __shfl_xor(s,  off);
        s2 += __shfl_xor(s2, off);
    }
    __shared__ float ls[4], ls2[4];
    int wid = threadIdx.x >> 6;
    if ((threadIdx.x & 63) == 0){ ls[wid] = s; ls2[wid] = s2; }
    __syncthreads();
    if (threadIdx.x == 0){
        float S = 0.f, S2 = 0.f;
        #pragma unroll
        for (int w = 0; w < 4; w++){ S += ls[w]; S2 += ls2[w]; }
        float m   = S * (1.f/S3);
        float var = S2 * (1.f/S3) - m*m;
        stats[c]       = m;
        stats[nch + c] = rsqrtf(var + EPS_IN);
    }
}

// ---------------- apply instance-norm + leaky (float4) ----------------
__global__ __launch_bounds__(256) void norm_apply_kernel(const float* __restrict__ xin,
                                                         const float* __restrict__ stats,
                                                         float* __restrict__ xout, int nch){
    int idx = blockIdx.x * 256 + threadIdx.x;       // float4 units
    int n4  = nch * (S3/4);
    if (idx >= n4) return;
    int c = idx >> 13;                               // /(S3/4)=8192
    float m = stats[c], r = stats[nch + c];
    float4 v = ((const float4*)xin)[idx];
    v.x = lrelu((v.x - m) * r);
    v.y = lrelu((v.y - m) * r);
    v.z = lrelu((v.z - m) * r);
    v.w = lrelu((v.w - m) * r);
    ((float4*)xout)[idx] = v;
}

// ---------------- direct 3x3x3 conv, pad 1 ----------------
// grid: (ceil(Cout/4), 32=z). block 256: thread t -> y=t>>3, x0=(t&7)*4, 4 outputs x 4 co.
__global__ __launch_bounds__(256) void conv3_kernel(const float* __restrict__ xin,
                                                    const float* __restrict__ wg,
                                                    const float* __restrict__ bg,
                                                    float* __restrict__ outp,
                                                    int Cin, int Cout){
    __shared__ float sIn[3*34*35];    // 3 z-planes, 34 rows, stride-35 cols (bank spread)
    int cog = blockIdx.x;
    int z   = blockIdx.y;
    int t   = threadIdx.x;
    int y   = t >> 3, x0 = (t & 7) * 4;

    int cg[4];
    #pragma unroll
    for (int co = 0; co < 4; co++){
        int c = cog*4 + co; if (c > Cout - 1) c = Cout - 1;
        cg[co] = __builtin_amdgcn_readfirstlane(c);
    }
    float acc[4][4];
    #pragma unroll
    for (int a = 0; a < 4; a++)
        #pragma unroll
        for (int b = 0; b < 4; b++) acc[a][b] = 0.f;

    for (int ci = 0; ci < Cin; ci++){
        for (int s = t; s < 3*34*35; s += 256){
            int pz = s / 1190; int r = s % 1190;
            int py = r / 35,   px = r % 35;
            int gz = z - 1 + pz, gy = py - 1, gx = px - 1;
            float v = 0.f;
            if (gz >= 0 && gz < 32 && gy >= 0 && gy < 32 && gx >= 0 && gx < 32)
                v = xin[(size_t)ci*S3 + (gz<<10) + (gy<<5) + gx];
            sIn[s] = v;
        }
        __syncthreads();
        #pragma unroll
        for (int kz = 0; kz < 3; kz++){
            #pragma unroll
            for (int ky = 0; ky < 3; ky++){
                int rb = kz*1190 + (y + ky)*35 + x0;
                float r0 = sIn[rb+0], r1 = sIn[rb+1], r2 = sIn[rb+2];
                float r3 = sIn[rb+3], r4 = sIn[rb+4], r5 = sIn[rb+5];
                #pragma unroll
                for (int co = 0; co < 4; co++){
                    const float* wp = wg + ((size_t)cg[co]*Cin + ci)*27 + kz*9 + ky*3;
                    float w0 = wp[0], w1 = wp[1], w2 = wp[2];
                    acc[co][0] += r0*w0 + r1*w1 + r2*w2;
                    acc[co][1] += r1*w0 + r2*w1 + r3*w2;
                    acc[co][2] += r2*w0 + r3*w1 + r4*w2;
                    acc[co][3] += r3*w0 + r4*w1 + r5*w2;
                }
            }
        }
        __syncthreads();
    }
    #pragma unroll
    for (int co = 0; co < 4; co++){
        int gco = cog*4 + co;
        if (gco < Cout){
            float b = bg[gco];
            float4 v = make_float4(acc[co][0]+b, acc[co][1]+b, acc[co][2]+b, acc[co][3]+b);
            *(float4*)(&outp[(size_t)gco*S3 + (z<<10) + (y<<5) + x0]) = v;
        }
    }
}

extern "C" void kernel_launch(void* const* d_in, const int* in_sizes, int n_in,
                              void* d_out, int out_size, void* d_ws, size_t ws_size,
                              hipStream_t stream) {
    const float* src   = (const float*)d_in[0];
    const float* tgt   = (const float*)d_in[1];
    const float* Cmat  = (const float*)d_in[2];
    const float* up_w  = (const float*)d_in[3];
    const float* up_b  = (const float*)d_in[4];
    const float* c1_w  = (const float*)d_in[5];
    const float* c1_b  = (const float*)d_in[6];
    const float* c2_w  = (const float*)d_in[7];
    const float* c2_b  = (const float*)d_in[8];
    const float* out_w = (const float*)d_in[9];
    const float* out_b = (const float*)d_in[10];

    float* out   = (float*)d_out;                       // Cn [219*S3] then out [3*S3]
    float* bufA  = (float*)d_ws;                        // 219*S3 floats (concat / normed)
    float* stats = bufA + (size_t)CC * S3;              // 2*CC (use 512 slots)
    float* srcp  = stats + 512;                         // 64*PADS floats

    // 1. upsample (pre-norm) -> out[0:64*S3]  (d_out used as scratch; overwritten later)
    upsample_kernel<<<dim3(64*32), 256, 0, stream>>>(Cmat, up_w, up_b, out);
    // 2. instance-norm stats over 64 channels
    stats_kernel<<<64, 256, 0, stream>>>(out, stats, 64);
    // 3. norm+leaky -> bufA channels [155..219)
    norm_apply_kernel<<<(64*(S3/4))/256, 256, 0, stream>>>(out, stats, bufA + (size_t)155*S3, 64);
    // 4. concat copies: tgt -> bufA[0:64), src -> bufA[64:128)
    copy4_kernel<<<(64*S3/4)/256, 256, 0, stream>>>((const float4*)tgt, (float4*)bufA, 64*S3/4);
    copy4_kernel<<<(64*S3/4)/256, 256, 0, stream>>>((const float4*)src, (float4*)(bufA + (size_t)64*S3), 64*S3/4);
    // 5. zero-padded src copy for correlation
    pad_kernel<<<(CF*PADS + 255)/256, 256, 0, stream>>>(src, srcp);
    // 6. correlation volume -> bufA channels [128..155)
    corr_kernel<<<S3/256, 256, 0, stream>>>(tgt, srcp, bufA);
    // 7. conv1 (219->219) : bufA -> out
    conv3_kernel<<<dim3(55, 32), 256, 0, stream>>>(bufA, c1_w, c1_b, out, CC, CC);
    // 8-9. instance-norm + leaky -> bufA
    stats_kernel<<<CC, 256, 0, stream>>>(out, stats, CC);
    norm_apply_kernel<<<(CC*(S3/4))/256, 256, 0, stream>>>(out, stats, bufA, CC);
    // 10. conv2 (219->219) : bufA -> out
    conv3_kernel<<<dim3(55, 32), 256, 0, stream>>>(bufA, c2_w, c2_b, out, CC, CC);
    // 11-12. instance-norm + leaky in-place -> Cn (final output 0)
    stats_kernel<<<CC, 256, 0, stream>>>(out, stats, CC);
    norm_apply_kernel<<<(CC*(S3/4))/256, 256, 0, stream>>>(out, stats, out, CC);
    // 13. out conv (219->3) : Cn -> out + 219*S3 (final output 1)
    conv3_kernel<<<dim3(1, 32), 256, 0, stream>>>(out, out_w, out_b, out + (size_t)CC*S3, CC, 3);
}

// Round 2
// 1073.784 us; speedup vs baseline: 7.4242x; 7.4242x over previous
//
#include <hip/hip_runtime.h>
#include <hip/hip_bf16.h>

#define S3 32768          // 32^3
#define PADD 34
#define PADS (34*34*34)   // 39304
#define CC 219
#define CF 64
#define CPAD 224          // padded channel count for conv inputs
#define CIN_UP 411
#define CUPAD 416         // padded channel count for upsample input
#define ALPHA 0.1f
#define EPS_IN 1e-5f

typedef __attribute__((ext_vector_type(8))) short short8;   // 8 bf16 (4 VGPRs)
typedef __attribute__((ext_vector_type(4))) float floatx4;  // 4 fp32 acc

__device__ __forceinline__ float lrelu(float v){ return v >= 0.f ? v : ALPHA * v; }
__device__ __forceinline__ unsigned short f2bf(float f){
    unsigned int u = __builtin_bit_cast(unsigned int, f);
    u = (u + 0x7FFFu + ((u >> 16) & 1u)) >> 16;   // RNE
    return (unsigned short)u;
}

// ---------------- zero-pad src to [64][34][34][34] fp32 (for corr) ----------------
__global__ __launch_bounds__(256) void pad_kernel(const float* __restrict__ src,
                                                  float* __restrict__ dst){
    int idx = blockIdx.x * 256 + threadIdx.x;
    if (idx >= CF * PADS) return;
    int c = idx / PADS, r = idx % PADS;
    int z = r / (PADD*PADD); int r2 = r % (PADD*PADD);
    int y = r2 / PADD, x = r2 % PADD;
    float v = 0.f;
    if (z >= 1 && z <= 32 && y >= 1 && y <= 32 && x >= 1 && x <= 32)
        v = src[((c*32 + (z-1))*32 + (y-1))*32 + (x-1)];
    dst[idx] = v;
}

// ---------------- correlation volume -> Xp channels [192..219) bf16 ----------------
__global__ __launch_bounds__(256) void corr_kernel(const float* __restrict__ tgt,
                                                   const float* __restrict__ srcp,
                                                   unsigned short* __restrict__ Xp){
    int p = blockIdx.x * 256 + threadIdx.x;   // 0..32767
    int z = p >> 10, y = (p >> 5) & 31, x = p & 31;
    float acc[27];
    #pragma unroll
    for (int k = 0; k < 27; k++) acc[k] = 0.f;
    int pbase = ((z+1)*PADD + (y+1))*PADD + (x+1);
    for (int c = 0; c < CF; c++){
        float t = tgt[c*S3 + p];
        const float* sp = srcp + c*PADS + pbase;
        #pragma unroll
        for (int dz = 0; dz < 3; dz++)
            #pragma unroll
            for (int dy = 0; dy < 3; dy++)
                #pragma unroll
                for (int dx = 0; dx < 3; dx++){
                    int k = (dz*3 + dy)*3 + dx;
                    acc[k] += t * sp[(dz-1)*(PADD*PADD) + (dy-1)*PADD + (dx-1)];
                }
    }
    unsigned short cv[27];
    #pragma unroll
    for (int k = 0; k < 27; k++) cv[k] = f2bf(acc[k] * (1.f/64.f));
    size_t bi = ((size_t)(z+1)*1156 + (y+1)*34 + (x+1))*CPAD + 192;
    uint4 o0, o1, o2;
    o0.x = cv[0]  | ((unsigned)cv[1]<<16);  o0.y = cv[2]  | ((unsigned)cv[3]<<16);
    o0.z = cv[4]  | ((unsigned)cv[5]<<16);  o0.w = cv[6]  | ((unsigned)cv[7]<<16);
    o1.x = cv[8]  | ((unsigned)cv[9]<<16);  o1.y = cv[10] | ((unsigned)cv[11]<<16);
    o1.z = cv[12] | ((unsigned)cv[13]<<16); o1.w = cv[14] | ((unsigned)cv[15]<<16);
    o2.x = cv[16] | ((unsigned)cv[17]<<16); o2.y = cv[18] | ((unsigned)cv[19]<<16);
    o2.z = cv[20] | ((unsigned)cv[21]<<16); o2.w = cv[22] | ((unsigned)cv[23]<<16);
    *(uint4*)&Xp[bi]      = o0;
    *(uint4*)&Xp[bi + 8]  = o1;
    *(uint4*)&Xp[bi + 16] = o2;
    *(unsigned int*)&Xp[bi + 24] = cv[24] | ((unsigned)cv[25]<<16);
    Xp[bi + 26] = cv[26];
}

// ---------------- instance-norm stats: one block per channel ----------------
__global__ __launch_bounds__(256) void stats_kernel(const float* __restrict__ xin,
                                                    float* __restrict__ stats, int nch){
    int c = blockIdx.x;
    const float* p = xin + (size_t)c * S3;
    float s = 0.f, s2 = 0.f;
    for (int i = threadIdx.x; i < S3; i += 256){
        float v = p[i];
        s += v; s2 += v*v;
    }
    #pragma unroll
    for (int off = 32; off > 0; off >>= 1){
        s  += __shfl_xor(s,  off);
        s2 += __shfl_xor(s2, off);
    }
    __shared__ float ls[4], ls2[4];
    int wid = threadIdx.x >> 6;
    if ((threadIdx.x & 63) == 0){ ls[wid] = s; ls2[wid] = s2; }
    __syncthreads();
    if (threadIdx.x == 0){
        float S = 0.f, S2 = 0.f;
        #pragma unroll
        for (int w = 0; w < 4; w++){ S += ls[w]; S2 += ls2[w]; }
        float m   = S * (1.f/S3);
        float var = S2 * (1.f/S3) - m*m;
        stats[c]       = m;
        stats[nch + c] = rsqrtf(var + EPS_IN);
    }
}

// ---------------- apply instance-norm + leaky (fp32, for final Cn) ----------------
__global__ __launch_bounds__(256) void norm_apply_kernel(const float* __restrict__ xin,
                                                         const float* __restrict__ stats,
                                                         float* __restrict__ xout, int nch){
    int idx = blockIdx.x * 256 + threadIdx.x;       // float4 units
    int n4  = nch * (S3/4);
    if (idx >= n4) return;
    int c = idx >> 13;
    float m = stats[c], r = stats[nch + c];
    float4 v = ((const float4*)xin)[idx];
    v.x = lrelu((v.x - m) * r);
    v.y = lrelu((v.y - m) * r);
    v.z = lrelu((v.z - m) * r);
    v.w = lrelu((v.w - m) * r);
    ((float4*)xout)[idx] = v;
}

// ---------------- pack fp32 [C][32^3] -> channel-last bf16 Xp[34^3][224] ----------------
// optional (norm + leaky). dstbase must be multiple of 8.
__global__ __launch_bounds__(256) void pack_kernel(const float* __restrict__ src,
        const float* __restrict__ mean, const float* __restrict__ rstd,
        unsigned short* __restrict__ Xp, int Csrc, int dstbase, int donorm){
    __shared__ float sT[64*33];
    const int row = blockIdx.x;          // z*32+y
    const int chunk = blockIdx.y;
    const int t = threadIdx.x;
    {
        int c = t >> 2, xq = (t & 3) * 8;
        int csrc = chunk*64 + c;
        float4 v0 = make_float4(0.f,0.f,0.f,0.f), v1 = v0;
        float m = 0.f, r = 1.f;
        if (csrc < Csrc){
            const float4* s4 = (const float4*)&src[(size_t)csrc*S3 + row*32 + xq];
            v0 = s4[0]; v1 = s4[1];
            if (donorm){ m = mean[csrc]; r = rstd[csrc]; }
        }
        if (donorm){
            v0.x = lrelu((v0.x-m)*r); v0.y = lrelu((v0.y-m)*r);
            v0.z = lrelu((v0.z-m)*r); v0.w = lrelu((v0.w-m)*r);
            v1.x = lrelu((v1.x-m)*r); v1.y = lrelu((v1.y-m)*r);
            v1.z = lrelu((v1.z-m)*r); v1.w = lrelu((v1.w-m)*r);
        }
        float* sp = &sT[c*33 + xq];
        sp[0]=v0.x; sp[1]=v0.y; sp[2]=v0.z; sp[3]=v0.w;
        sp[4]=v1.x; sp[5]=v1.y; sp[6]=v1.z; sp[7]=v1.w;
    }
    __syncthreads();
    {
        int x = t >> 3, coff = (t & 7) * 8;
        int dstc = dstbase + chunk*64 + coff;
        if (dstc < CPAD){
            unsigned short u[8];
            #pragma unroll
            for (int j = 0; j < 8; j++) u[j] = f2bf(sT[(coff+j)*33 + x]);
            uint4 o;
            o.x = u[0] | ((unsigned)u[1]<<16);
            o.y = u[2] | ((unsigned)u[3]<<16);
            o.z = u[4] | ((unsigned)u[5]<<16);
            o.w = u[6] | ((unsigned)u[7]<<16);
            int z = row >> 5, y = row & 31;
            size_t pos = (size_t)(z+1)*1156 + (y+1)*34 + (x+1);
            *(uint4*)&Xp[pos*CPAD + dstc] = o;
        }
    }
}

// ---------------- pack fp32 [411][16^3] -> channel-last bf16 Cp[18^3][416] ----------------
__global__ __launch_bounds__(256) void pack16_kernel(const float* __restrict__ src,
        unsigned short* __restrict__ Cp){
    __shared__ float sT[64*17];
    const int row = blockIdx.x;   // z'*16+y'
    const int chunk = blockIdx.y; // 0..6
    const int t = threadIdx.x;
    {
        int c = t >> 2, xq = (t & 3) * 4;
        int csrc = chunk*64 + c;
        float4 v = make_float4(0.f,0.f,0.f,0.f);
        if (csrc < CIN_UP)
            v = *(const float4*)&src[(size_t)csrc*4096 + row*16 + xq];
        float* sp = &sT[c*17 + xq];
        sp[0]=v.x; sp[1]=v.y; sp[2]=v.z; sp[3]=v.w;
    }
    __syncthreads();
    {
        int x = t >> 4, coff = (t & 15) * 4;
        int dstc = chunk*64 + coff;
        if (dstc < CUPAD){
            unsigned short u0 = f2bf(sT[(coff+0)*17 + x]);
            unsigned short u1 = f2bf(sT[(coff+1)*17 + x]);
            unsigned short u2 = f2bf(sT[(coff+2)*17 + x]);
            unsigned short u3 = f2bf(sT[(coff+3)*17 + x]);
            uint2 o; o.x = u0 | ((unsigned)u1<<16); o.y = u2 | ((unsigned)u3<<16);
            int z = row >> 4, y = row & 15;
            size_t pos = (size_t)(z+1)*324 + (y+1)*18 + (x+1);
            *(uint2*)&Cp[pos*CUPAD + dstc] = o;
        }
    }
}

// ---------------- pack conv weights: Wt[tap][cb][co 256][ci 32] bf16 ----------------
// perm: our ci order = [tgt 0..127][Cup 128..191][cost 192..218] -> ref concat order
__global__ __launch_bounds__(256) void wpack_kernel(const float* __restrict__ w,
        unsigned short* __restrict__ Wt, int perm){
    int idx = blockIdx.x*256 + threadIdx.x;   // < 27*7*256*32
    int ciin = idx & 31;
    int co   = (idx >> 5) & 255;
    int rest = idx >> 13;        // tap*7+cb
    int cb = rest % 7, tap = rest / 7;
    int ci = cb*32 + ciin;
    float v = 0.f;
    if (co < CC && ci < CC){
        int ciref = ci;
        if (perm) ciref = ci < 128 ? ci : (ci < 192 ? ci + 27 : ci - 64);
        v = w[((size_t)co*CC + ciref)*27 + tap];
    }
    Wt[idx] = f2bf(v);
}

// ---------------- pack upsample weights: Wu[parity 8][tap 8][co 64][ci 416] bf16 ----------------
__global__ __launch_bounds__(256) void wupack_kernel(const float* __restrict__ w,
        unsigned short* __restrict__ Wu){
    int idx = blockIdx.x*256 + threadIdx.x;  // < 8*8*64*416
    int ci = idx % CUPAD;
    int rest = idx / CUPAD;
    int co = rest & 63;
    int pj = rest >> 6;
    int j = pj & 7, p = pj >> 3;
    float v = 0.f;
    if (ci < CIN_UP){
        int oz = p>>2, oy = (p>>1)&1, ox = p&1;
        int jz = j>>2, jy = (j>>1)&1, jx = j&1;
        int wz = 3 - oz - 2*jz, wy = 3 - oy - 2*jy, wx = 3 - ox - 2*jx;
        v = w[(((size_t)ci*64 + co)*64) + wz*16 + wy*4 + wx];
    }
    Wu[idx] = f2bf(v);
}

// ---------------- upsample via MFMA: per-parity GEMM M=64, N=16^3, K=8*416 ----------------
__global__ __launch_bounds__(256,2) void ups_mfma_kernel(const unsigned short* __restrict__ Cp,
        const unsigned short* __restrict__ Wu, float* __restrict__ U){
    __shared__ unsigned short sA[64*40];
    __shared__ unsigned short sB[64*40];
    const int nt = blockIdx.x;          // 512 = parity(8) x z'(16) x ygrp(4)
    const int p  = nt >> 6;
    const int zp = (nt >> 2) & 15;
    const int y0 = (nt & 3) * 4;
    const int oz = p>>2, oy = (p>>1)&1, ox = p&1;
    const int t = threadIdx.x, w = t>>6, l = t&63;
    const int mw = (w&1)*32, nw = (w>>1)*32;
    const int lm = l&15, lq = l>>4;
    const int sn = t>>2, spart = (t&3)*8;
    const int sr = sn>>4, sx = sn&15;
    floatx4 acc[2][2];
    #pragma unroll
    for (int i=0;i<2;i++)
        #pragma unroll
        for (int j=0;j<2;j++) acc[i][j] = (floatx4){0.f,0.f,0.f,0.f};

    for (int j = 0; j < 8; ++j){
        int sz = oz + (j>>2), sy = oy + ((j>>1)&1), sxx = ox + (j&1);
        size_t pbase = ((size_t)(zp+sz)*324 + (y0+sr+sy)*18 + (sx+sxx)) * CUPAD;
        size_t abase = ((size_t)(p*8 + j)*64 + sn)*CUPAD;
        for (int cb = 0; cb < 13; ++cb){
            uint4 av = *(const uint4*)&Wu[abase + cb*32 + spart];
            uint4 bv = *(const uint4*)&Cp[pbase + cb*32 + spart];
            *(uint4*)&sA[sn*40 + spart] = av;
            *(uint4*)&sB[sn*40 + spart] = bv;
            __syncthreads();
            short8 af[2], bfv[2];
            #pragma unroll
            for (int i=0;i<2;i++){
                af[i]  = *(const short8*)&sA[(mw + i*16 + lm)*40 + lq*8];
                bfv[i] = *(const short8*)&sB[(nw + i*16 + lm)*40 + lq*8];
            }
            #pragma unroll
            for (int i=0;i<2;i++)
                #pragma unroll
                for (int jj=0;jj<2;jj++)
                    acc[i][jj] = __builtin_amdgcn_mfma_f32_16x16x32_bf16(af[i], bfv[jj], acc[i][jj], 0,0,0);
            __syncthreads();
        }
    }
    #pragma unroll
    for (int i=0;i<2;i++){
        #pragma unroll
        for (int jj=0;jj<2;jj++){
            int n = nw + jj*16 + lm;
            int yy = y0 + (n>>4), xx = n&15;
            size_t opos = ((size_t)(2*zp+oz)<<10) + ((size_t)(2*yy+oy)<<5) + (2*xx+ox);
            #pragma unroll
            for (int r=0;r<4;r++){
                int co = mw + i*16 + lq*4 + r;
                U[(size_t)co*S3 + opos] = acc[i][jj][r];
            }
        }
    }
}

// ---------------- 3x3x3 conv via MFMA: 128x128 block tile, K = 27 taps x 7 ci-chunks ----------------
__global__ __launch_bounds__(256,2) void conv_mfma_kernel(const unsigned short* __restrict__ Xp,
        const unsigned short* __restrict__ Wt, const float* __restrict__ bg,
        float* __restrict__ Y){
    __shared__ unsigned short sA[128*40];
    __shared__ unsigned short sB[128*40];
    const int nt = blockIdx.x;     // 0..255: z(32) x ygrp(8)
    const int mt = blockIdx.y;     // 0..1
    const int z  = nt >> 3;
    const int y0 = (nt & 7) * 4;
    const int t = threadIdx.x, w = t>>6, l = t&63;
    const int mw = (w & 1) * 64, nw = (w >> 1) * 64;
    const int lm = l & 15, lq = l >> 4;
    const int sco  = t >> 1;            // A row (co) / B row (n)
    const int shalf= (t & 1) * 16;      // ci element offset
    const int srow = sco >> 5;          // B: y-row within tile
    const int sx   = sco & 31;          // B: x

    floatx4 acc[4][4];
    #pragma unroll
    for (int i=0;i<4;i++)
        #pragma unroll
        for (int j=0;j<4;j++) acc[i][j] = (floatx4){0.f,0.f,0.f,0.f};

    for (int tap = 0; tap < 27; ++tap){
        const int dz = tap / 9, dy = (tap / 3) % 3, dx = tap % 3;
        const size_t pbase = ((size_t)(z + dz)*1156 + (y0 + srow + dy)*34 + (sx + dx)) * CPAD;
        #pragma unroll 1
        for (int cb = 0; cb < 7; ++cb){
            const unsigned short* ga = Wt + ((size_t)((tap*7 + cb)*256) + mt*128 + sco)*32 + shalf;
            uint4 a0 = *(const uint4*)ga;
            uint4 a1 = *(const uint4*)(ga + 8);
            const unsigned short* gb = Xp + pbase + cb*32 + shalf;
            uint4 b0 = *(const uint4*)gb;
            uint4 b1 = *(const uint4*)(gb + 8);
            *(uint4*)&sA[sco*40 + shalf]     = a0;
            *(uint4*)&sA[sco*40 + shalf + 8] = a1;
            *(uint4*)&sB[sco*40 + shalf]     = b0;
            *(uint4*)&sB[sco*40 + shalf + 8] = b1;
            __syncthreads();
            short8 af[4], bfv[4];
            #pragma unroll
            for (int i=0;i<4;i++){
                af[i]  = *(const short8*)&sA[(mw + i*16 + lm)*40 + lq*8];
                bfv[i] = *(const short8*)&sB[(nw + i*16 + lm)*40 + lq*8];
            }
            #pragma unroll
            for (int i=0;i<4;i++)
                #pragma unroll
                for (int j=0;j<4;j++)
                    acc[i][j] = __builtin_amdgcn_mfma_f32_16x16x32_bf16(af[i], bfv[j], acc[i][j], 0,0,0);
            __syncthreads();
        }
    }
    #pragma unroll
    for (int i=0;i<4;i++){
        #pragma unroll
        for (int j=0;j<4;j++){
            const int n = nw + j*16 + lm;
            const size_t pp = ((size_t)z<<10) + ((size_t)(y0 + (n>>5))<<5) + (n&31);
            #pragma unroll
            for (int r=0;r<4;r++){
                int gm = mt*128 + mw + i*16 + lq*4 + r;
                if (gm < CC) Y[(size_t)gm*S3 + pp] = acc[i][j][r] + bg[gm];
            }
        }
    }
}

// ---------------- final 219->3 conv, fp32 direct ----------------
__global__ __launch_bounds__(256) void convout_kernel(const float* __restrict__ xin,
        const float* __restrict__ wg, const float* __restrict__ bgl,
        float* __restrict__ outp){
    __shared__ float sIn[3*10*35];
    const int ygrp = blockIdx.x;     // 0..3
    const int z = blockIdx.y;        // 0..31
    const int t = threadIdx.x;
    const int w = t>>6, l = t&63;
    const int co = w < 3 ? w : 2;
    const int y = l>>3, x0 = (l&7)*4;
    const int y0 = ygrp*8;
    float acc0=0.f, acc1=0.f, acc2=0.f, acc3=0.f;
    for (int ci = 0; ci < CC; ++ci){
        for (int s = t; s < 1050; s += 256){
            int pz = s/350, r = s%350, py = r/35, px = r%35;
            int gz = z-1+pz, gy = y0-1+py, gx = px-1;
            float v = 0.f;
            if (gz>=0 && gz<32 && gy>=0 && gy<32 && gx>=0 && gx<32 && px<34)
                v = xin[(size_t)ci*S3 + (gz<<10) + (gy<<5) + gx];
            sIn[s] = v;
        }
        __syncthreads();
        if (w < 3){
            const float* wp0 = wg + ((size_t)co*CC + ci)*27;
            #pragma unroll
            for (int kz=0; kz<3; kz++){
                #pragma unroll
                for (int ky=0; ky<3; ky++){
                    int rb = kz*350 + (y+ky)*35 + x0;
                    float r0=sIn[rb],r1=sIn[rb+1],r2=sIn[rb+2],r3=sIn[rb+3],r4=sIn[rb+4],r5=sIn[rb+5];
                    float w0=wp0[kz*9+ky*3], w1=wp0[kz*9+ky*3+1], w2=wp0[kz*9+ky*3+2];
                    acc0 += r0*w0 + r1*w1 + r2*w2;
                    acc1 += r1*w0 + r2*w1 + r3*w2;
                    acc2 += r2*w0 + r3*w1 + r4*w2;
                    acc3 += r3*w0 + r4*w1 + r5*w2;
                }
            }
        }
        __syncthreads();
    }
    if (w < 3){
        float b = bgl[co];
        float4 v = make_float4(acc0+b, acc1+b, acc2+b, acc3+b);
        *(float4*)(&outp[(size_t)co*S3 + (z<<10) + ((y0+y)<<5) + x0]) = v;
    }
}

extern "C" void kernel_launch(void* const* d_in, const int* in_sizes, int n_in,
                              void* d_out, int out_size, void* d_ws, size_t ws_size,
                              hipStream_t stream) {
    const float* src   = (const float*)d_in[0];
    const float* tgt   = (const float*)d_in[1];
    const float* Cmat  = (const float*)d_in[2];
    const float* up_w  = (const float*)d_in[3];
    const float* c1_w  = (const float*)d_in[5];
    const float* c1_b  = (const float*)d_in[6];
    const float* c2_w  = (const float*)d_in[7];
    const float* c2_b  = (const float*)d_in[8];
    const float* out_w = (const float*)d_in[9];
    const float* out_b = (const float*)d_in[10];

    float* out = (float*)d_out;                          // Cn [219*S3] then out [3*S3]
    char* ws = (char*)d_ws;
    unsigned short* Xp = (unsigned short*)ws;            // 34^3 x 224 bf16 = 17,608,192 B
    float*  U  = (float*)(ws + 17608192);                // 64*S3 fp32 = 8,388,608 B
    unsigned short* Wt = (unsigned short*)(ws + 17608192);       // aliases U (3,096,576 B)
    unsigned short* Cp = (unsigned short*)(ws + 25996800);       // 18^3 x 416 bf16 = 4,852,224 B
    unsigned short* Wu = (unsigned short*)(ws + 25996800 + 4852224); // 3,407,872 B
    float* srcp = (float*)(ws + 25996800);               // aliases Cp/Wu (10,061,824 B)
    float* stats = (float*)(ws + 36058624);              // 2 KB

    hipMemsetAsync(Xp, 0, 17608192, stream);             // halo + pad channels
    hipMemsetAsync(Cp, 0, 4852224, stream);

    // ---- upsample (411->64, k4 s2) as 8 parity GEMMs + instance-norm + leaky ----
    pack16_kernel<<<dim3(256,7), 256, 0, stream>>>(Cmat, Cp);
    wupack_kernel<<<6656, 256, 0, stream>>>(up_w, Wu);
    ups_mfma_kernel<<<512, 256, 0, stream>>>(Cp, Wu, U);
    stats_kernel<<<64, 256, 0, stream>>>(U, stats, 64);
    pack_kernel<<<dim3(1024,1), 256, 0, stream>>>(U, stats, stats+64, Xp, 64, 128, 1); // Cup -> ch 128..191
    // ---- concat: tgt -> ch 0..63, src -> ch 64..127 (raw) ----
    pack_kernel<<<dim3(1024,1), 256, 0, stream>>>(tgt, nullptr, nullptr, Xp, 64, 0, 0);
    pack_kernel<<<dim3(1024,1), 256, 0, stream>>>(src, nullptr, nullptr, Xp, 64, 64, 0);
    // ---- correlation volume -> ch 192..218 ----
    pad_kernel<<<9826, 256, 0, stream>>>(src, srcp);
    corr_kernel<<<128, 256, 0, stream>>>(tgt, srcp, Xp);
    // ---- conv1 (219->219) MFMA ----
    wpack_kernel<<<6048, 256, 0, stream>>>(c1_w, Wt, 1);
    conv_mfma_kernel<<<dim3(256,2), 256, 0, stream>>>(Xp, Wt, c1_b, out);
    stats_kernel<<<219, 256, 0, stream>>>(out, stats, 219);
    pack_kernel<<<dim3(1024,4), 256, 0, stream>>>(out, stats, stats+219, Xp, 219, 0, 1);
    // ---- conv2 (219->219) MFMA ----
    wpack_kernel<<<6048, 256, 0, stream>>>(c2_w, Wt, 0);
    conv_mfma_kernel<<<dim3(256,2), 256, 0, stream>>>(Xp, Wt, c2_b, out);
    stats_kernel<<<219, 256, 0, stream>>>(out, stats, 219);
    norm_apply_kernel<<<(219*(S3/4))/256, 256, 0, stream>>>(out, stats, out, 219);
    // ---- final 219->3 conv ----
    convout_kernel<<<dim3(4,32), 256, 0, stream>>>(out, out_w, out_b, out + (size_t)CC*S3);
}

// Round 3
// 763.979 us; speedup vs baseline: 10.4349x; 1.4055x over previous
//
#include <hip/hip_runtime.h>
#include <hip/hip_bf16.h>

#define S3 32768          // 32^3
#define PADD 34
#define PADS (34*34*34)   // 39304
#define CC 219
#define CF 64
#define CPAD 224          // padded channel count for conv inputs
#define CIN_UP 411
#define CUPAD 416         // padded channel count for upsample input
#define ALPHA 0.1f
#define EPS_IN 1e-5f

typedef __attribute__((ext_vector_type(8))) short short8;   // 8 bf16 (4 VGPRs)
typedef __attribute__((ext_vector_type(4))) float floatx4;  // 4 fp32 acc

__device__ __forceinline__ float lrelu(float v){ return v >= 0.f ? v : ALPHA * v; }
__device__ __forceinline__ unsigned short f2bf(float f){
    unsigned int u = __builtin_bit_cast(unsigned int, f);
    u = (u + 0x7FFFu + ((u >> 16) & 1u)) >> 16;   // RNE
    return (unsigned short)u;
}

// ---------------- zero-pad src to [64][34][34][34] fp32 (for corr) ----------------
__global__ __launch_bounds__(256) void pad_kernel(const float* __restrict__ src,
                                                  float* __restrict__ dst){
    int idx = blockIdx.x * 256 + threadIdx.x;
    if (idx >= CF * PADS) return;
    int c = idx / PADS, r = idx % PADS;
    int z = r / (PADD*PADD); int r2 = r % (PADD*PADD);
    int y = r2 / PADD, x = r2 % PADD;
    float v = 0.f;
    if (z >= 1 && z <= 32 && y >= 1 && y <= 32 && x >= 1 && x <= 32)
        v = src[((c*32 + (z-1))*32 + (y-1))*32 + (x-1)];
    dst[idx] = v;
}

// ---------------- correlation volume -> Xp channels [192..219) bf16 ----------------
__global__ __launch_bounds__(256) void corr_kernel(const float* __restrict__ tgt,
                                                   const float* __restrict__ srcp,
                                                   unsigned short* __restrict__ Xp){
    int p = blockIdx.x * 256 + threadIdx.x;   // 0..32767
    int z = p >> 10, y = (p >> 5) & 31, x = p & 31;
    float acc[27];
    #pragma unroll
    for (int k = 0; k < 27; k++) acc[k] = 0.f;
    int pbase = ((z+1)*PADD + (y+1))*PADD + (x+1);
    for (int c = 0; c < CF; c++){
        float t = tgt[c*S3 + p];
        const float* sp = srcp + c*PADS + pbase;
        #pragma unroll
        for (int dz = 0; dz < 3; dz++)
            #pragma unroll
            for (int dy = 0; dy < 3; dy++)
                #pragma unroll
                for (int dx = 0; dx < 3; dx++){
                    int k = (dz*3 + dy)*3 + dx;
                    acc[k] += t * sp[(dz-1)*(PADD*PADD) + (dy-1)*PADD + (dx-1)];
                }
    }
    unsigned short cv[27];
    #pragma unroll
    for (int k = 0; k < 27; k++) cv[k] = f2bf(acc[k] * (1.f/64.f));
    size_t bi = ((size_t)(z+1)*1156 + (y+1)*34 + (x+1))*CPAD + 192;
    uint4 o0, o1, o2;
    o0.x = cv[0]  | ((unsigned)cv[1]<<16);  o0.y = cv[2]  | ((unsigned)cv[3]<<16);
    o0.z = cv[4]  | ((unsigned)cv[5]<<16);  o0.w = cv[6]  | ((unsigned)cv[7]<<16);
    o1.x = cv[8]  | ((unsigned)cv[9]<<16);  o1.y = cv[10] | ((unsigned)cv[11]<<16);
    o1.z = cv[12] | ((unsigned)cv[13]<<16); o1.w = cv[14] | ((unsigned)cv[15]<<16);
    o2.x = cv[16] | ((unsigned)cv[17]<<16); o2.y = cv[18] | ((unsigned)cv[19]<<16);
    o2.z = cv[20] | ((unsigned)cv[21]<<16); o2.w = cv[22] | ((unsigned)cv[23]<<16);
    *(uint4*)&Xp[bi]      = o0;
    *(uint4*)&Xp[bi + 8]  = o1;
    *(uint4*)&Xp[bi + 16] = o2;
    *(unsigned int*)&Xp[bi + 24] = cv[24] | ((unsigned)cv[25]<<16);
    Xp[bi + 26] = cv[26];
}

// ---------------- instance-norm stats: one block per channel ----------------
__global__ __launch_bounds__(256) void stats_kernel(const float* __restrict__ xin,
                                                    float* __restrict__ stats, int nch){
    int c = blockIdx.x;
    const float* p = xin + (size_t)c * S3;
    float s = 0.f, s2 = 0.f;
    for (int i = threadIdx.x; i < S3; i += 256){
        float v = p[i];
        s += v; s2 += v*v;
    }
    #pragma unroll
    for (int off = 32; off > 0; off >>= 1){
        s  += __shfl_xor(s,  off);
        s2 += __shfl_xor(s2, off);
    }
    __shared__ float ls[4], ls2[4];
    int wid = threadIdx.x >> 6;
    if ((threadIdx.x & 63) == 0){ ls[wid] = s; ls2[wid] = s2; }
    __syncthreads();
    if (threadIdx.x == 0){
        float S = 0.f, S2 = 0.f;
        #pragma unroll
        for (int w = 0; w < 4; w++){ S += ls[w]; S2 += ls2[w]; }
        float m   = S * (1.f/S3);
        float var = S2 * (1.f/S3) - m*m;
        stats[c]       = m;
        stats[nch + c] = rsqrtf(var + EPS_IN);
    }
}

// ---------------- apply instance-norm + leaky (fp32, for final Cn) ----------------
__global__ __launch_bounds__(256) void norm_apply_kernel(const float* __restrict__ xin,
                                                         const float* __restrict__ stats,
                                                         float* __restrict__ xout, int nch){
    int idx = blockIdx.x * 256 + threadIdx.x;       // float4 units
    int n4  = nch * (S3/4);
    if (idx >= n4) return;
    int c = idx >> 13;
    float m = stats[c], r = stats[nch + c];
    float4 v = ((const float4*)xin)[idx];
    v.x = lrelu((v.x - m) * r);
    v.y = lrelu((v.y - m) * r);
    v.z = lrelu((v.z - m) * r);
    v.w = lrelu((v.w - m) * r);
    ((float4*)xout)[idx] = v;
}

// ---------------- pack fp32 [C][32^3] -> channel-last bf16 Xp[34^3][224] ----------------
// optional (norm + leaky). dstbase must be multiple of 8.
__global__ __launch_bounds__(256) void pack_kernel(const float* __restrict__ src,
        const float* __restrict__ mean, const float* __restrict__ rstd,
        unsigned short* __restrict__ Xp, int Csrc, int dstbase, int donorm){
    __shared__ float sT[64*33];
    const int row = blockIdx.x;          // z*32+y
    const int chunk = blockIdx.y;
    const int t = threadIdx.x;
    {
        int c = t >> 2, xq = (t & 3) * 8;
        int csrc = chunk*64 + c;
        float4 v0 = make_float4(0.f,0.f,0.f,0.f), v1 = v0;
        float m = 0.f, r = 1.f;
        if (csrc < Csrc){
            const float4* s4 = (const float4*)&src[(size_t)csrc*S3 + row*32 + xq];
            v0 = s4[0]; v1 = s4[1];
            if (donorm){ m = mean[csrc]; r = rstd[csrc]; }
        }
        if (donorm){
            v0.x = lrelu((v0.x-m)*r); v0.y = lrelu((v0.y-m)*r);
            v0.z = lrelu((v0.z-m)*r); v0.w = lrelu((v0.w-m)*r);
            v1.x = lrelu((v1.x-m)*r); v1.y = lrelu((v1.y-m)*r);
            v1.z = lrelu((v1.z-m)*r); v1.w = lrelu((v1.w-m)*r);
        }
        float* sp = &sT[c*33 + xq];
        sp[0]=v0.x; sp[1]=v0.y; sp[2]=v0.z; sp[3]=v0.w;
        sp[4]=v1.x; sp[5]=v1.y; sp[6]=v1.z; sp[7]=v1.w;
    }
    __syncthreads();
    {
        int x = t >> 3, coff = (t & 7) * 8;
        int dstc = dstbase + chunk*64 + coff;
        if (dstc < CPAD){
            unsigned short u[8];
            #pragma unroll
            for (int j = 0; j < 8; j++) u[j] = f2bf(sT[(coff+j)*33 + x]);
            uint4 o;
            o.x = u[0] | ((unsigned)u[1]<<16);
            o.y = u[2] | ((unsigned)u[3]<<16);
            o.z = u[4] | ((unsigned)u[5]<<16);
            o.w = u[6] | ((unsigned)u[7]<<16);
            int z = row >> 5, y = row & 31;
            size_t pos = (size_t)(z+1)*1156 + (y+1)*34 + (x+1);
            *(uint4*)&Xp[pos*CPAD + dstc] = o;
        }
    }
}

// ---------------- pack fp32 [411][16^3] -> channel-last bf16 Cp[18^3][416] ----------------
__global__ __launch_bounds__(256) void pack16_kernel(const float* __restrict__ src,
        unsigned short* __restrict__ Cp){
    __shared__ float sT[64*17];
    const int row = blockIdx.x;   // z'*16+y'
    const int chunk = blockIdx.y; // 0..6
    const int t = threadIdx.x;
    {
        int c = t >> 2, xq = (t & 3) * 4;
        int csrc = chunk*64 + c;
        float4 v = make_float4(0.f,0.f,0.f,0.f);
        if (csrc < CIN_UP)
            v = *(const float4*)&src[(size_t)csrc*4096 + row*16 + xq];
        float* sp = &sT[c*17 + xq];
        sp[0]=v.x; sp[1]=v.y; sp[2]=v.z; sp[3]=v.w;
    }
    __syncthreads();
    {
        int x = t >> 4, coff = (t & 15) * 4;
        int dstc = chunk*64 + coff;
        if (dstc < CUPAD){
            unsigned short u0 = f2bf(sT[(coff+0)*17 + x]);
            unsigned short u1 = f2bf(sT[(coff+1)*17 + x]);
            unsigned short u2 = f2bf(sT[(coff+2)*17 + x]);
            unsigned short u3 = f2bf(sT[(coff+3)*17 + x]);
            uint2 o; o.x = u0 | ((unsigned)u1<<16); o.y = u2 | ((unsigned)u3<<16);
            int z = row >> 4, y = row & 15;
            size_t pos = (size_t)(z+1)*324 + (y+1)*18 + (x+1);
            *(uint2*)&Cp[pos*CUPAD + dstc] = o;
        }
    }
}

// ---------------- pack conv weights: Wt[tap][cb][co 256][ci 32] bf16 ----------------
// perm: our ci order = [tgt 0..127][Cup 128..191][cost 192..218] -> ref concat order
__global__ __launch_bounds__(256) void wpack_kernel(const float* __restrict__ w,
        unsigned short* __restrict__ Wt, int perm){
    int idx = blockIdx.x*256 + threadIdx.x;   // < 27*7*256*32
    int ciin = idx & 31;
    int co   = (idx >> 5) & 255;
    int rest = idx >> 13;        // tap*7+cb
    int cb = rest % 7, tap = rest / 7;
    int ci = cb*32 + ciin;
    float v = 0.f;
    if (co < CC && ci < CC){
        int ciref = ci;
        if (perm) ciref = ci < 128 ? ci : (ci < 192 ? ci + 27 : ci - 64);
        v = w[((size_t)co*CC + ciref)*27 + tap];
    }
    Wt[idx] = f2bf(v);
}

// ---------------- pack out-conv weights: Wt2[tap][cb][co 16][ci 32] bf16 ----------------
__global__ __launch_bounds__(256) void wpack_out_kernel(const float* __restrict__ w,
        unsigned short* __restrict__ Wt2){
    int idx = blockIdx.x*256 + threadIdx.x;   // < 27*7*16*32 = 96768
    if (idx >= 27*7*16*32) return;
    int ciin = idx & 31;
    int co   = (idx >> 5) & 15;
    int rest = idx >> 9;        // tap*7+cb
    int cb = rest % 7, tap = rest / 7;
    int ci = cb*32 + ciin;
    float v = 0.f;
    if (co < 3 && ci < CC)
        v = w[((size_t)co*CC + ci)*27 + tap];
    Wt2[idx] = f2bf(v);
}

// ---------------- pack upsample weights: Wu[parity 8][tap 8][co 64][ci 416] bf16 ----------------
__global__ __launch_bounds__(256) void wupack_kernel(const float* __restrict__ w,
        unsigned short* __restrict__ Wu){
    int idx = blockIdx.x*256 + threadIdx.x;  // < 8*8*64*416
    int ci = idx % CUPAD;
    int rest = idx / CUPAD;
    int co = rest & 63;
    int pj = rest >> 6;
    int j = pj & 7, p = pj >> 3;
    float v = 0.f;
    if (ci < CIN_UP){
        int oz = p>>2, oy = (p>>1)&1, ox = p&1;
        int jz = j>>2, jy = (j>>1)&1, jx = j&1;
        int wz = 3 - oz - 2*jz, wy = 3 - oy - 2*jy, wx = 3 - ox - 2*jx;
        v = w[(((size_t)ci*64 + co)*64) + wz*16 + wy*4 + wx];
    }
    Wu[idx] = f2bf(v);
}

// ---------------- upsample via MFMA: per-parity GEMM M=64, N=16^3, K=8*416 ----------------
__global__ __launch_bounds__(256,2) void ups_mfma_kernel(const unsigned short* __restrict__ Cp,
        const unsigned short* __restrict__ Wu, float* __restrict__ U){
    __shared__ unsigned short sA[64*40];
    __shared__ unsigned short sB[64*40];
    const int nt = blockIdx.x;          // 512 = parity(8) x z'(16) x ygrp(4)
    const int p  = nt >> 6;
    const int zp = (nt >> 2) & 15;
    const int y0 = (nt & 3) * 4;
    const int oz = p>>2, oy = (p>>1)&1, ox = p&1;
    const int t = threadIdx.x, w = t>>6, l = t&63;
    const int mw = (w&1)*32, nw = (w>>1)*32;
    const int lm = l&15, lq = l>>4;
    const int sn = t>>2, spart = (t&3)*8;
    const int sr = sn>>4, sx = sn&15;
    floatx4 acc[2][2];
    #pragma unroll
    for (int i=0;i<2;i++)
        #pragma unroll
        for (int j=0;j<2;j++) acc[i][j] = (floatx4){0.f,0.f,0.f,0.f};

    for (int j = 0; j < 8; ++j){
        int sz = oz + (j>>2), sy = oy + ((j>>1)&1), sxx = ox + (j&1);
        size_t pbase = ((size_t)(zp+sz)*324 + (y0+sr+sy)*18 + (sx+sxx)) * CUPAD;
        size_t abase = ((size_t)(p*8 + j)*64 + sn)*CUPAD;
        for (int cb = 0; cb < 13; ++cb){
            uint4 av = *(const uint4*)&Wu[abase + cb*32 + spart];
            uint4 bv = *(const uint4*)&Cp[pbase + cb*32 + spart];
            *(uint4*)&sA[sn*40 + spart] = av;
            *(uint4*)&sB[sn*40 + spart] = bv;
            __syncthreads();
            short8 af[2], bfv[2];
            #pragma unroll
            for (int i=0;i<2;i++){
                af[i]  = *(const short8*)&sA[(mw + i*16 + lm)*40 + lq*8];
                bfv[i] = *(const short8*)&sB[(nw + i*16 + lm)*40 + lq*8];
            }
            #pragma unroll
            for (int i=0;i<2;i++)
                #pragma unroll
                for (int jj=0;jj<2;jj++)
                    acc[i][jj] = __builtin_amdgcn_mfma_f32_16x16x32_bf16(af[i], bfv[jj], acc[i][jj], 0,0,0);
            __syncthreads();
        }
    }
    #pragma unroll
    for (int i=0;i<2;i++){
        #pragma unroll
        for (int jj=0;jj<2;jj++){
            int n = nw + jj*16 + lm;
            int yy = y0 + (n>>4), xx = n&15;
            size_t opos = ((size_t)(2*zp+oz)<<10) + ((size_t)(2*yy+oy)<<5) + (2*xx+ox);
            #pragma unroll
            for (int r=0;r<4;r++){
                int co = mw + i*16 + lq*4 + r;
                U[(size_t)co*S3 + opos] = acc[i][jj][r];
            }
        }
    }
}

// ---------------- 3x3x3 conv via MFMA: 128x128 block tile, K = 27 taps x 7 ci-chunks ----------------
__global__ __launch_bounds__(256,2) void conv_mfma_kernel(const unsigned short* __restrict__ Xp,
        const unsigned short* __restrict__ Wt, const float* __restrict__ bg,
        float* __restrict__ Y){
    __shared__ unsigned short sA[128*40];
    __shared__ unsigned short sB[128*40];
    const int nt = blockIdx.x;     // 0..255: z(32) x ygrp(8)
    const int mt = blockIdx.y;     // 0..1
    const int z  = nt >> 3;
    const int y0 = (nt & 7) * 4;
    const int t = threadIdx.x, w = t>>6, l = t&63;
    const int mw = (w & 1) * 64, nw = (w >> 1) * 64;
    const int lm = l & 15, lq = l >> 4;
    const int sco  = t >> 1;            // A row (co) / B row (n)
    const int shalf= (t & 1) * 16;      // ci element offset
    const int srow = sco >> 5;          // B: y-row within tile
    const int sx   = sco & 31;          // B: x

    floatx4 acc[4][4];
    #pragma unroll
    for (int i=0;i<4;i++)
        #pragma unroll
        for (int j=0;j<4;j++) acc[i][j] = (floatx4){0.f,0.f,0.f,0.f};

    for (int tap = 0; tap < 27; ++tap){
        const int dz = tap / 9, dy = (tap / 3) % 3, dx = tap % 3;
        const size_t pbase = ((size_t)(z + dz)*1156 + (y0 + srow + dy)*34 + (sx + dx)) * CPAD;
        #pragma unroll 1
        for (int cb = 0; cb < 7; ++cb){
            const unsigned short* ga = Wt + ((size_t)((tap*7 + cb)*256) + mt*128 + sco)*32 + shalf;
            uint4 a0 = *(const uint4*)ga;
            uint4 a1 = *(const uint4*)(ga + 8);
            const unsigned short* gb = Xp + pbase + cb*32 + shalf;
            uint4 b0 = *(const uint4*)gb;
            uint4 b1 = *(const uint4*)(gb + 8);
            *(uint4*)&sA[sco*40 + shalf]     = a0;
            *(uint4*)&sA[sco*40 + shalf + 8] = a1;
            *(uint4*)&sB[sco*40 + shalf]     = b0;
            *(uint4*)&sB[sco*40 + shalf + 8] = b1;
            __syncthreads();
            short8 af[4], bfv[4];
            #pragma unroll
            for (int i=0;i<4;i++){
                af[i]  = *(const short8*)&sA[(mw + i*16 + lm)*40 + lq*8];
                bfv[i] = *(const short8*)&sB[(nw + i*16 + lm)*40 + lq*8];
            }
            #pragma unroll
            for (int i=0;i<4;i++)
                #pragma unroll
                for (int j=0;j<4;j++)
                    acc[i][j] = __builtin_amdgcn_mfma_f32_16x16x32_bf16(af[i], bfv[j], acc[i][j], 0,0,0);
            __syncthreads();
        }
    }
    #pragma unroll
    for (int i=0;i<4;i++){
        #pragma unroll
        for (int j=0;j<4;j++){
            const int n = nw + j*16 + lm;
            const size_t pp = ((size_t)z<<10) + ((size_t)(y0 + (n>>5))<<5) + (n&31);
            #pragma unroll
            for (int r=0;r<4;r++){
                int gm = mt*128 + mw + i*16 + lq*4 + r;
                if (gm < CC) Y[(size_t)gm*S3 + pp] = acc[i][j][r] + bg[gm];
            }
        }
    }
}

// ---------------- final 219->3 conv via MFMA: M=16 tile, N=128/block ----------------
__global__ __launch_bounds__(256,2) void convout_mfma_kernel(const unsigned short* __restrict__ Xp,
        const unsigned short* __restrict__ Wt2, const float* __restrict__ bgl,
        float* __restrict__ Y){
    __shared__ unsigned short sA[16*40];
    __shared__ unsigned short sB[128*40];
    const int nt = blockIdx.x;      // z(32) x ygrp(8)
    const int z  = nt >> 3;
    const int y0 = (nt & 7) * 4;
    const int t = threadIdx.x, w = t>>6, l = t&63;
    const int nw = w * 32;
    const int lm = l & 15, lq = l >> 4;
    const int sco  = t >> 1;
    const int shalf= (t & 1) * 16;
    const int srow = sco >> 5;
    const int sx   = sco & 31;
    floatx4 acc[2];
    acc[0] = (floatx4){0.f,0.f,0.f,0.f};
    acc[1] = (floatx4){0.f,0.f,0.f,0.f};

    for (int tap = 0; tap < 27; ++tap){
        const int dz = tap / 9, dy = (tap / 3) % 3, dx = tap % 3;
        const size_t pbase = ((size_t)(z + dz)*1156 + (y0 + srow + dy)*34 + (sx + dx)) * CPAD;
        #pragma unroll 1
        for (int cb = 0; cb < 7; ++cb){
            const unsigned short* gb = Xp + pbase + cb*32 + shalf;
            uint4 b0 = *(const uint4*)gb;
            uint4 b1 = *(const uint4*)(gb + 8);
            uint4 a0, a1;
            if (t < 32){
                const unsigned short* ga = Wt2 + ((size_t)((tap*7 + cb)*16) + sco)*32 + shalf;
                a0 = *(const uint4*)ga;
                a1 = *(const uint4*)(ga + 8);
            }
            *(uint4*)&sB[sco*40 + shalf]     = b0;
            *(uint4*)&sB[sco*40 + shalf + 8] = b1;
            if (t < 32){
                *(uint4*)&sA[sco*40 + shalf]     = a0;
                *(uint4*)&sA[sco*40 + shalf + 8] = a1;
            }
            __syncthreads();
            short8 af = *(const short8*)&sA[lm*40 + lq*8];
            #pragma unroll
            for (int j = 0; j < 2; j++){
                short8 bf = *(const short8*)&sB[(nw + j*16 + lm)*40 + lq*8];
                acc[j] = __builtin_amdgcn_mfma_f32_16x16x32_bf16(af, bf, acc[j], 0,0,0);
            }
            __syncthreads();
        }
    }
    if (lq == 0){
        #pragma unroll
        for (int j = 0; j < 2; j++){
            int n = nw + j*16 + lm;
            size_t pp = ((size_t)z<<10) + ((size_t)(y0 + (n>>5))<<5) + (n&31);
            #pragma unroll
            for (int r = 0; r < 3; r++)
                Y[(size_t)r*S3 + pp] = acc[j][r] + bgl[r];
        }
    }
}

extern "C" void kernel_launch(void* const* d_in, const int* in_sizes, int n_in,
                              void* d_out, int out_size, void* d_ws, size_t ws_size,
                              hipStream_t stream) {
    const float* src   = (const float*)d_in[0];
    const float* tgt   = (const float*)d_in[1];
    const float* Cmat  = (const float*)d_in[2];
    const float* up_w  = (const float*)d_in[3];
    const float* c1_w  = (const float*)d_in[5];
    const float* c1_b  = (const float*)d_in[6];
    const float* c2_w  = (const float*)d_in[7];
    const float* c2_b  = (const float*)d_in[8];
    const float* out_w = (const float*)d_in[9];
    const float* out_b = (const float*)d_in[10];

    float* out = (float*)d_out;                          // Cn [219*S3] then out [3*S3]
    char* ws = (char*)d_ws;
    unsigned short* Xp = (unsigned short*)ws;            // 34^3 x 224 bf16 = 17,608,192 B
    float*  U  = (float*)(ws + 17608192);                // 64*S3 fp32 = 8,388,608 B
    unsigned short* Wt = (unsigned short*)(ws + 17608192);       // aliases U (3,096,576 B)
    unsigned short* Cp = (unsigned short*)(ws + 25996800);       // 18^3 x 416 bf16 = 4,852,224 B
    unsigned short* Wu = (unsigned short*)(ws + 25996800 + 4852224); // 3,407,872 B
    float* srcp = (float*)(ws + 25996800);               // aliases Cp/Wu (10,061,824 B)
    unsigned short* Wt2 = (unsigned short*)(ws + 25996800); // aliases srcp after corr (193,536 B)
    float* stats = (float*)(ws + 36058624);              // 2 KB

    hipMemsetAsync(Xp, 0, 17608192, stream);             // halo + pad channels
    hipMemsetAsync(Cp, 0, 4852224, stream);

    // ---- upsample (411->64, k4 s2) as 8 parity GEMMs + instance-norm + leaky ----
    pack16_kernel<<<dim3(256,7), 256, 0, stream>>>(Cmat, Cp);
    wupack_kernel<<<6656, 256, 0, stream>>>(up_w, Wu);
    ups_mfma_kernel<<<512, 256, 0, stream>>>(Cp, Wu, U);
    stats_kernel<<<64, 256, 0, stream>>>(U, stats, 64);
    pack_kernel<<<dim3(1024,1), 256, 0, stream>>>(U, stats, stats+64, Xp, 64, 128, 1); // Cup -> ch 128..191
    // ---- concat: tgt -> ch 0..63, src -> ch 64..127 (raw) ----
    pack_kernel<<<dim3(1024,1), 256, 0, stream>>>(tgt, nullptr, nullptr, Xp, 64, 0, 0);
    pack_kernel<<<dim3(1024,1), 256, 0, stream>>>(src, nullptr, nullptr, Xp, 64, 64, 0);
    // ---- correlation volume -> ch 192..218 ----
    pad_kernel<<<9826, 256, 0, stream>>>(src, srcp);
    corr_kernel<<<128, 256, 0, stream>>>(tgt, srcp, Xp);
    // ---- out-conv weight pack (srcp region is free after corr) ----
    wpack_out_kernel<<<378, 256, 0, stream>>>(out_w, Wt2);
    // ---- conv1 (219->219) MFMA ----
    wpack_kernel<<<6048, 256, 0, stream>>>(c1_w, Wt, 1);
    conv_mfma_kernel<<<dim3(256,2), 256, 0, stream>>>(Xp, Wt, c1_b, out);
    stats_kernel<<<219, 256, 0, stream>>>(out, stats, 219);
    pack_kernel<<<dim3(1024,4), 256, 0, stream>>>(out, stats, stats+219, Xp, 219, 0, 1);
    // ---- conv2 (219->219) MFMA ----
    wpack_kernel<<<6048, 256, 0, stream>>>(c2_w, Wt, 0);
    conv_mfma_kernel<<<dim3(256,2), 256, 0, stream>>>(Xp, Wt, c2_b, out);
    // ---- norm + leaky: fp32 Cn to d_out, bf16 packed Cn to Xp ----
    stats_kernel<<<219, 256, 0, stream>>>(out, stats, 219);
    pack_kernel<<<dim3(1024,4), 256, 0, stream>>>(out, stats, stats+219, Xp, 219, 0, 1);
    norm_apply_kernel<<<(219*(S3/4))/256, 256, 0, stream>>>(out, stats, out, 219);
    // ---- final 219->3 conv via MFMA ----
    convout_mfma_kernel<<<256, 256, 0, stream>>>(Xp, Wt2, out_b, out + (size_t)CC*S3);
}